// Round 1
// baseline (1102.084 us; speedup 1.0000x reference)
//
#include <hip/hip_runtime.h>
#include <hip/hip_bf16.h>

typedef unsigned short u16;
typedef unsigned int u32;
typedef __attribute__((ext_vector_type(8))) short bf16x8;   // 8 bf16 in 4 VGPRs
typedef __attribute__((ext_vector_type(4))) float f32x4;

#define T_TOKENS 50176   // 2*128*196
#define D_MODEL  1024
#define D_INNER  2048
#define D_STATE  8

__device__ __forceinline__ u16 f2bf(float f) {
    u32 u = __builtin_bit_cast(u32, f);
    u += 0x7fffu + ((u >> 16) & 1u);   // RNE
    return (u16)(u >> 16);
}
__device__ __forceinline__ float bf2f(u16 h) {
    u32 u = ((u32)h) << 16;
    return __builtin_bit_cast(float, u);
}
__device__ __forceinline__ float silu(float v) {
    return v / (1.f + __expf(-v));
}

// ---------------------------------------------------------------- K1: LayerNorm -> bf16
__global__ __launch_bounds__(256) void k_ln(const float* __restrict__ x,
                                            const float* __restrict__ gamma,
                                            const float* __restrict__ beta,
                                            u16* __restrict__ xn) {
    const int w = threadIdx.x >> 6, lane = threadIdx.x & 63;
    const int tok = blockIdx.x * 4 + w;                 // 12544 blocks * 4 waves = 50176
    const float* xr = x + (size_t)tok * D_MODEL;
    float4 v[4];
    float s1 = 0.f, s2 = 0.f;
#pragma unroll
    for (int c = 0; c < 4; ++c) {
        v[c] = *(const float4*)(xr + c * 256 + lane * 4);
        s1 += v[c].x + v[c].y + v[c].z + v[c].w;
        s2 += v[c].x * v[c].x + v[c].y * v[c].y + v[c].z * v[c].z + v[c].w * v[c].w;
    }
#pragma unroll
    for (int off = 32; off; off >>= 1) {
        s1 += __shfl_xor(s1, off, 64);
        s2 += __shfl_xor(s2, off, 64);
    }
    const float mu = s1 * (1.f / 1024.f);
    const float var = s2 * (1.f / 1024.f) - mu * mu;
    const float rstd = rsqrtf(var + 1e-5f);
    u16* orow = xn + (size_t)tok * D_MODEL;
#pragma unroll
    for (int c = 0; c < 4; ++c) {
        const int d = c * 256 + lane * 4;
        float4 g = *(const float4*)(gamma + d);
        float4 b = *(const float4*)(beta + d);
        ushort4 o;
        o.x = f2bf((v[c].x - mu) * rstd * g.x + b.x);
        o.y = f2bf((v[c].y - mu) * rstd * g.y + b.y);
        o.z = f2bf((v[c].z - mu) * rstd * g.z + b.z);
        o.w = f2bf((v[c].w - mu) * rstd * g.w + b.w);
        *(ushort4*)(orow + d) = o;
    }
}

// ---------------------------------------------------------------- K1b: W_proj fp32 -> bf16
__global__ __launch_bounds__(256) void k_cvt(const float* __restrict__ W, u16* __restrict__ Wb) {
    const int i = (blockIdx.x * 256 + threadIdx.x) * 4;   // 2048 blocks covers 2048*1024
    float4 v = *(const float4*)(W + i);
    ushort4 o = {f2bf(v.x), f2bf(v.y), f2bf(v.z), f2bf(v.w)};
    *(ushort4*)(Wb + i) = o;
}

// ---------------------------------------------------------------- K2: bf16 GEMM (B^T), +b_proj, store bf16
// A [T,1024] bf16, B=W_proj [2048,1024] bf16.  Tile 128x128, BK=64, 4 waves (2x2 of 64x64).
__global__ __launch_bounds__(256) void k_gemm(const u16* __restrict__ A,
                                              const u16* __restrict__ B,
                                              const float* __restrict__ bproj,
                                              u16* __restrict__ P) {
    __shared__ u16 As[128 * 64];
    __shared__ u16 Bs[128 * 64];
    const int t = threadIdx.x;
    const int w = t >> 6, lane = t & 63;
    const int q = lane >> 4, c15 = lane & 15;
    const int bn = blockIdx.x, bm = blockIdx.y;
    const int wm = (w >> 1) * 64, wn = (w & 1) * 64;

    f32x4 acc[4][4];
#pragma unroll
    for (int i = 0; i < 4; ++i)
#pragma unroll
        for (int j = 0; j < 4; ++j) acc[i][j] = (f32x4){0.f, 0.f, 0.f, 0.f};

    // staging coords: 256 thr * 16B = 32 rows/issue; XOR swizzle chunk^=(row&7)
    const int srow = t >> 3;
    const int sch = (t & 7) ^ (srow & 7);
    const u16* Ag = A + (size_t)(bm * 128 + srow) * 1024 + sch * 8;
    const u16* Bg = B + (size_t)(bn * 128 + srow) * 1024 + sch * 8;
    u16* lA = &As[t * 8];
    u16* lB = &Bs[t * 8];

    for (int kb = 0; kb < 16; ++kb) {
        __syncthreads();
#pragma unroll
        for (int i = 0; i < 4; ++i) {
            __builtin_amdgcn_global_load_lds(
                (const __attribute__((address_space(1))) void*)(Ag + (size_t)i * 32 * 1024 + kb * 64),
                (__attribute__((address_space(3))) void*)(lA + i * 2048), 16, 0, 0);
            __builtin_amdgcn_global_load_lds(
                (const __attribute__((address_space(1))) void*)(Bg + (size_t)i * 32 * 1024 + kb * 64),
                (__attribute__((address_space(3))) void*)(lB + i * 2048), 16, 0, 0);
        }
        __syncthreads();
#pragma unroll
        for (int ks = 0; ks < 2; ++ks) {
            bf16x8 af[4], bfr[4];
            const int chb = (ks * 4 + q) ^ (c15 & 7);
#pragma unroll
            for (int mi = 0; mi < 4; ++mi)
                af[mi] = *(const bf16x8*)&As[(wm + mi * 16 + c15) * 64 + chb * 8];
#pragma unroll
            for (int ni = 0; ni < 4; ++ni)
                bfr[ni] = *(const bf16x8*)&Bs[(wn + ni * 16 + c15) * 64 + chb * 8];
#pragma unroll
            for (int mi = 0; mi < 4; ++mi)
#pragma unroll
                for (int ni = 0; ni < 4; ++ni)
                    acc[mi][ni] = __builtin_amdgcn_mfma_f32_16x16x32_bf16(af[mi], bfr[ni], acc[mi][ni], 0, 0, 0);
        }
    }
    // epilogue: +b_proj, cast bf16, store (pre-SiLU)
#pragma unroll
    for (int ni = 0; ni < 4; ++ni) {
        const int col = bn * 128 + wn + ni * 16 + c15;
        const float bp = bproj[col];
#pragma unroll
        for (int mi = 0; mi < 4; ++mi) {
            const int row = bm * 128 + wm + mi * 16 + q * 4;
#pragma unroll
            for (int r = 0; r < 4; ++r)
                P[(size_t)(row + r) * D_INNER + col] = f2bf(acc[mi][ni][r] + bp);
        }
    }
}

// ---------------------------------------------------------------- K3: silu, xW_state^T, silu, xW_out^T, +x
__global__ __launch_bounds__(256) void k_out(const float* __restrict__ x,
                                             const float* __restrict__ Wstate,  // [8][2048]
                                             const float* __restrict__ bstate,  // [8]
                                             const float* __restrict__ Wout,    // [1024][8]
                                             const float* __restrict__ bout,    // [1024]
                                             const float* __restrict__ s0,      // [8]
                                             float* out,                        // low 2 bytes: proj bf16
                                             int nblocks) {
    __shared__ u16 wsl[D_INNER * 8];   // W_state bf16, [e][n], slot e^((e>>3)&7)
    __shared__ u16 wol[D_MODEL * 8];   // W_out   bf16, [d][n], slot d^((d>>2)&7)
    const int t = threadIdx.x;
    for (int i = 0; i < 8; ++i) {
        const int e = i * 256 + t;
        const int se = e ^ ((e >> 3) & 7);
#pragma unroll
        for (int n = 0; n < 8; ++n) wsl[se * 8 + n] = f2bf(Wstate[n * D_INNER + e]);
    }
    for (int i = 0; i < 4; ++i) {
        const int d = i * 256 + t;
        const int sd = d ^ ((d >> 2) & 7);
#pragma unroll
        for (int n = 0; n < 8; ++n) wol[sd * 8 + n] = f2bf(Wout[d * 8 + n]);
    }
    float shift[8];
#pragma unroll
    for (int n = 0; n < 8; ++n) shift[n] = s0[n] + bstate[n];
    __syncthreads();

    const int w = t >> 6, lane = t & 63;
    const u16* P = (const u16*)out;
    for (int tok = blockIdx.x * 4 + w; tok < T_TOKENS; tok += nblocks * 4) {
        float su[8] = {0.f, 0.f, 0.f, 0.f, 0.f, 0.f, 0.f, 0.f};
        const u16* prow = P + (size_t)tok * D_INNER;
#pragma unroll
        for (int c = 0; c < 4; ++c) {
            const int e0 = c * 512 + lane * 8;
            bf16x8 p8 = *(const bf16x8*)(prow + e0);
#pragma unroll
            for (int j = 0; j < 8; ++j) {
                const float sp = silu(bf2f((u16)p8[j]));
                const int e = e0 + j;
                const int se = e ^ ((e >> 3) & 7);
                bf16x8 w8 = *(const bf16x8*)&wsl[se * 8];
#pragma unroll
                for (int n = 0; n < 8; ++n) su[n] += sp * bf2f((u16)w8[n]);
            }
        }
#pragma unroll
        for (int off = 32; off; off >>= 1)
#pragma unroll
            for (int n = 0; n < 8; ++n) su[n] += __shfl_xor(su[n], off, 64);
        float cs[8];
#pragma unroll
        for (int n = 0; n < 8; ++n) cs[n] = silu(su[n] + shift[n]);

        const float* xr = x + (size_t)tok * D_MODEL;
        float* orow = out + (size_t)tok * D_MODEL;
#pragma unroll
        for (int c = 0; c < 4; ++c) {
            const int d0 = c * 256 + lane * 4;
            float4 xv = *(const float4*)(xr + d0);
            float4 ov;
#pragma unroll
            for (int dd = 0; dd < 4; ++dd) {
                const int d = d0 + dd;
                const int sd = d ^ ((d >> 2) & 7);
                bf16x8 wo = *(const bf16x8*)&wol[sd * 8];
                float a = (&xv.x)[dd] + bout[d];
#pragma unroll
                for (int n = 0; n < 8; ++n) a += cs[n] * bf2f((u16)wo[n]);
                (&ov.x)[dd] = a;
            }
            *(float4*)(orow + d0) = ov;
        }
    }
}

extern "C" void kernel_launch(void* const* d_in, const int* in_sizes, int n_in,
                              void* d_out, int out_size, void* d_ws, size_t ws_size,
                              hipStream_t stream) {
    const float* x      = (const float*)d_in[0];
    const float* Wproj  = (const float*)d_in[1];
    const float* bproj  = (const float*)d_in[2];
    const float* Wstate = (const float*)d_in[3];
    const float* bstate = (const float*)d_in[4];
    const float* Wout   = (const float*)d_in[5];
    const float* bout   = (const float*)d_in[6];
    const float* s0     = (const float*)d_in[7];
    const float* gamma  = (const float*)d_in[8];
    const float* beta   = (const float*)d_in[9];

    u16* xn = (u16*)d_ws;                           // 50176*1024 bf16 = 102.8 MB
    u16* Wb = xn + (size_t)T_TOKENS * D_MODEL;      // 2048*1024 bf16 = 4 MB
    u16* P  = (u16*)d_out;                          // proj bf16 lives in d_out, overwritten by K3
    float* out = (float*)d_out;

    k_ln  <<<T_TOKENS / 4, 256, 0, stream>>>(x, gamma, beta, xn);
    k_cvt <<<(D_INNER * D_MODEL) / 1024, 256, 0, stream>>>(Wproj, Wb);
    k_gemm<<<dim3(D_INNER / 128, T_TOKENS / 128), 256, 0, stream>>>(xn, Wb, bproj, P);
    k_out <<<1568, 256, 0, stream>>>(x, Wstate, bstate, Wout, bout, s0, out, 1568);
}

// Round 2
// 840.629 us; speedup vs baseline: 1.3110x; 1.3110x over previous
//
#include <hip/hip_runtime.h>
#include <hip/hip_bf16.h>

typedef unsigned short u16;
typedef unsigned int u32;
typedef __attribute__((ext_vector_type(8))) short bf16x8;   // 8 bf16 in 4 VGPRs
typedef __attribute__((ext_vector_type(4))) float f32x4;

#define T_TOKENS 50176   // 2*128*196
#define D_MODEL  1024
#define D_INNER  2048
#define D_STATE  8

__device__ __forceinline__ u16 f2bf(float f) {
    u32 u = __builtin_bit_cast(u32, f);
    u += 0x7fffu + ((u >> 16) & 1u);   // RNE
    return (u16)(u >> 16);
}
__device__ __forceinline__ float bf2f(u16 h) {
    u32 u = ((u32)h) << 16;
    return __builtin_bit_cast(float, u);
}
__device__ __forceinline__ float silu(float v) {
    return v / (1.f + __expf(-v));
}

// ---------------------------------------------------------------- K1: LayerNorm -> bf16 (into d_out)
__global__ __launch_bounds__(256) void k_ln(const float* __restrict__ x,
                                            const float* __restrict__ gamma,
                                            const float* __restrict__ beta,
                                            u16* __restrict__ xn) {
    const int w = threadIdx.x >> 6, lane = threadIdx.x & 63;
    const int tok = blockIdx.x * 4 + w;                 // 12544 blocks * 4 waves = 50176
    const float* xr = x + (size_t)tok * D_MODEL;
    float4 v[4];
    float s1 = 0.f, s2 = 0.f;
#pragma unroll
    for (int c = 0; c < 4; ++c) {
        v[c] = *(const float4*)(xr + c * 256 + lane * 4);
        s1 += v[c].x + v[c].y + v[c].z + v[c].w;
        s2 += v[c].x * v[c].x + v[c].y * v[c].y + v[c].z * v[c].z + v[c].w * v[c].w;
    }
#pragma unroll
    for (int off = 32; off; off >>= 1) {
        s1 += __shfl_xor(s1, off, 64);
        s2 += __shfl_xor(s2, off, 64);
    }
    const float mu = s1 * (1.f / 1024.f);
    const float var = s2 * (1.f / 1024.f) - mu * mu;
    const float rstd = rsqrtf(var + 1e-5f);
    u16* orow = xn + (size_t)tok * D_MODEL;
#pragma unroll
    for (int c = 0; c < 4; ++c) {
        const int d = c * 256 + lane * 4;
        float4 g = *(const float4*)(gamma + d);
        float4 b = *(const float4*)(beta + d);
        ushort4 o;
        o.x = f2bf((v[c].x - mu) * rstd * g.x + b.x);
        o.y = f2bf((v[c].y - mu) * rstd * g.y + b.y);
        o.z = f2bf((v[c].z - mu) * rstd * g.z + b.z);
        o.w = f2bf((v[c].w - mu) * rstd * g.w + b.w);
        *(ushort4*)(orow + d) = o;
    }
}

// ---------------------------------------------------------------- K1b: W_proj fp32 -> bf16
__global__ __launch_bounds__(256) void k_cvt(const float* __restrict__ W, u16* __restrict__ Wb) {
    const int i = (blockIdx.x * 256 + threadIdx.x) * 4;   // 2048 blocks covers 2048*1024
    float4 v = *(const float4*)(W + i);
    ushort4 o = {f2bf(v.x), f2bf(v.y), f2bf(v.z), f2bf(v.w)};
    *(ushort4*)(Wb + i) = o;
}

// ---------------------------------------------------------------- K2: bf16 GEMM + fused silu*W_state^T partial reduce
// A [T,1024] bf16, B=W_proj [2048,1024] bf16.  Tile 128x128, BK=64, 4 waves (2x2 of 64x64).
// Output: partials[T][32][8] fp32, slot index = bn*2 + (wave&1).
__global__ __launch_bounds__(256) void k_gemm(const u16* __restrict__ A,
                                              const u16* __restrict__ B,
                                              const float* __restrict__ bproj,
                                              const float* __restrict__ Wstate,   // [8][2048] fp32
                                              float* __restrict__ part) {
    __shared__ u16 As[128 * 64];
    __shared__ u16 Bs[128 * 64];
    const int t = threadIdx.x;
    const int w = t >> 6, lane = t & 63;
    const int q = lane >> 4, c15 = lane & 15;
    const int bn = blockIdx.x, bm = blockIdx.y;
    const int wm = (w >> 1) * 64, wn = (w & 1) * 64;

    f32x4 acc[4][4];
#pragma unroll
    for (int i = 0; i < 4; ++i)
#pragma unroll
        for (int j = 0; j < 4; ++j) acc[i][j] = (f32x4){0.f, 0.f, 0.f, 0.f};

    // staging coords: 256 thr * 16B = 32 rows/issue; XOR swizzle chunk^=(row&7)
    const int srow = t >> 3;
    const int sch = (t & 7) ^ (srow & 7);
    const u16* Ag = A + (size_t)(bm * 128 + srow) * 1024 + sch * 8;
    const u16* Bg = B + (size_t)(bn * 128 + srow) * 1024 + sch * 8;
    u16* lA = &As[t * 8];
    u16* lB = &Bs[t * 8];

    for (int kb = 0; kb < 16; ++kb) {
        __syncthreads();
#pragma unroll
        for (int i = 0; i < 4; ++i) {
            __builtin_amdgcn_global_load_lds(
                (const __attribute__((address_space(1))) void*)(Ag + (size_t)i * 32 * 1024 + kb * 64),
                (__attribute__((address_space(3))) void*)(lA + i * 2048), 16, 0, 0);
            __builtin_amdgcn_global_load_lds(
                (const __attribute__((address_space(1))) void*)(Bg + (size_t)i * 32 * 1024 + kb * 64),
                (__attribute__((address_space(3))) void*)(lB + i * 2048), 16, 0, 0);
        }
        __syncthreads();
#pragma unroll
        for (int ks = 0; ks < 2; ++ks) {
            bf16x8 af[4], bfr[4];
            const int chb = (ks * 4 + q) ^ (c15 & 7);
#pragma unroll
            for (int mi = 0; mi < 4; ++mi)
                af[mi] = *(const bf16x8*)&As[(wm + mi * 16 + c15) * 64 + chb * 8];
#pragma unroll
            for (int ni = 0; ni < 4; ++ni)
                bfr[ni] = *(const bf16x8*)&Bs[(wn + ni * 16 + c15) * 64 + chb * 8];
#pragma unroll
            for (int mi = 0; mi < 4; ++mi)
#pragma unroll
                for (int ni = 0; ni < 4; ++ni)
                    acc[mi][ni] = __builtin_amdgcn_mfma_f32_16x16x32_bf16(af[mi], bfr[ni], acc[mi][ni], 0, 0, 0);
        }
    }

    // ---- fused epilogue: sv = silu(acc + b_proj); ps[row][n] = sum_cols sv * W_state[n][col]
    float wsv[4][8], bp[4];
#pragma unroll
    for (int ni = 0; ni < 4; ++ni) {
        const int col = bn * 128 + wn + ni * 16 + c15;
        bp[ni] = bproj[col];
#pragma unroll
        for (int n = 0; n < 8; ++n) wsv[ni][n] = Wstate[n * D_INNER + col];
    }
    const int slot = bn * 2 + (w & 1);
#pragma unroll
    for (int mi = 0; mi < 4; ++mi) {
        float ps[4][8];
#pragma unroll
        for (int r = 0; r < 4; ++r)
#pragma unroll
            for (int n = 0; n < 8; ++n) ps[r][n] = 0.f;
#pragma unroll
        for (int ni = 0; ni < 4; ++ni)
#pragma unroll
            for (int r = 0; r < 4; ++r) {
                const float sv = silu(acc[mi][ni][r] + bp[ni]);
#pragma unroll
                for (int n = 0; n < 8; ++n) ps[r][n] += sv * wsv[ni][n];
            }
        // reduce over the 16 c15 lanes (xor offsets stay within q-group)
#pragma unroll
        for (int off = 1; off < 16; off <<= 1)
#pragma unroll
            for (int r = 0; r < 4; ++r)
#pragma unroll
                for (int n = 0; n < 8; ++n) ps[r][n] += __shfl_xor(ps[r][n], off, 64);
        if (c15 < 8) {
            const int n = c15;
#pragma unroll
            for (int r = 0; r < 4; ++r) {
                float v = ps[r][0];
#pragma unroll
                for (int j = 1; j < 8; ++j) v = (n == j) ? ps[r][j] : v;
                const int row = bm * 128 + wm + mi * 16 + q * 4 + r;
                part[(size_t)row * 256 + slot * 8 + n] = v;
            }
        }
    }
}

// ---------------------------------------------------------------- K3: sum partials, silu, xW_out^T, +x
__global__ __launch_bounds__(256) void k_out2(const float* __restrict__ x,
                                              const float* __restrict__ part,   // [T][32][8]
                                              const float* __restrict__ Wout,   // [1024][8]
                                              const float* __restrict__ bout,   // [1024]
                                              const float* __restrict__ bstate, // [8]
                                              const float* __restrict__ s0,     // [8]
                                              float* __restrict__ out) {
    // W_out in LDS as 16B slots, swizzled: slot(d,h) = (d*2+h) ^ ((d>>2)&7)
    __shared__ float4 wol[2048];   // 32 KB
    const int t = threadIdx.x;
    const float4* Wg4 = (const float4*)Wout;
#pragma unroll
    for (int i = 0; i < 8; ++i) {
        const int g = i * 256 + t;
        const int d = g >> 1;
        wol[g ^ ((d >> 2) & 7)] = Wg4[g];
    }
    __syncthreads();

    const int w = t >> 6, lane = t & 63;
    const int tok = blockIdx.x * 4 + w;

    // partials: 256 f32 per token = 64 float4, one per lane; butterfly-reduce (parity-preserving)
    const float4* p4 = (const float4*)(part + (size_t)tok * 256);
    float4 pv = p4[lane];
    float pa[4] = {pv.x, pv.y, pv.z, pv.w};
#pragma unroll
    for (int off = 2; off < 64; off <<= 1)
#pragma unroll
        for (int j = 0; j < 4; ++j) pa[j] += __shfl_xor(pa[j], off, 64);
    float cs[8];
#pragma unroll
    for (int j = 0; j < 4; ++j) {
        const float sl = __shfl(pa[j], 0, 64);          // states 0..3 on even lanes
        const float sh = __shfl(pa[j], 1, 64);          // states 4..7 on odd lanes
        cs[j]     = silu(sl + s0[j]     + bstate[j]);
        cs[4 + j] = silu(sh + s0[4 + j] + bstate[4 + j]);
    }

    const float* xr = x + (size_t)tok * D_MODEL;
    float* orow = out + (size_t)tok * D_MODEL;
#pragma unroll
    for (int c = 0; c < 16; ++c) {
        const int d = c * 64 + lane;
        const int m = (d >> 2) & 7;
        const float4 w0 = wol[(d * 2) ^ m];
        const float4 w1 = wol[(d * 2 + 1) ^ m];
        float a = xr[d] + bout[d];
        a += cs[0] * w0.x + cs[1] * w0.y + cs[2] * w0.z + cs[3] * w0.w;
        a += cs[4] * w1.x + cs[5] * w1.y + cs[6] * w1.z + cs[7] * w1.w;
        orow[d] = a;
    }
}

extern "C" void kernel_launch(void* const* d_in, const int* in_sizes, int n_in,
                              void* d_out, int out_size, void* d_ws, size_t ws_size,
                              hipStream_t stream) {
    const float* x      = (const float*)d_in[0];
    const float* Wproj  = (const float*)d_in[1];
    const float* bproj  = (const float*)d_in[2];
    const float* Wstate = (const float*)d_in[3];
    const float* bstate = (const float*)d_in[4];
    const float* Wout   = (const float*)d_in[5];
    const float* bout   = (const float*)d_in[6];
    const float* s0     = (const float*)d_in[7];
    const float* gamma  = (const float*)d_in[8];
    const float* beta   = (const float*)d_in[9];

    u16* xn = (u16*)d_out;                               // LN output (bf16) borrows d_out;
                                                         // fully consumed by k_gemm before k_out2 overwrites
    u16* Wb = (u16*)d_ws;                                // 4 MB
    float* partials = (float*)((char*)d_ws + (size_t)D_INNER * D_MODEL * sizeof(u16));  // 51.4 MB
    float* out = (float*)d_out;

    k_ln  <<<T_TOKENS / 4, 256, 0, stream>>>(x, gamma, beta, xn);
    k_cvt <<<(D_INNER * D_MODEL) / 1024, 256, 0, stream>>>(Wproj, Wb);
    k_gemm<<<dim3(D_INNER / 128, T_TOKENS / 128), 256, 0, stream>>>(xn, Wb, bproj, Wstate, partials);
    k_out2<<<T_TOKENS / 4, 256, 0, stream>>>(x, partials, Wout, bout, bstate, s0, out);
}